// Round 8
// baseline (94.870 us; speedup 1.0000x reference)
//
#include <hip/hip_runtime.h>
#include <stdint.h>

typedef float f32x2 __attribute__((ext_vector_type(2)));
typedef float f32x4 __attribute__((ext_vector_type(4)));

__device__ __forceinline__ float leaky(float v) { return fmaxf(v, 0.01f * v); }

// One thread = one row, end to end. No LDS, no barriers, no cross-lane ops.
// All weight/bias indices are wave-uniform -> s_load (scalar pipe) broadcast.
__global__ __launch_bounds__(256, 2) void gen_mlp_r8(
    const float* __restrict__ x, const float* __restrict__ data_t,
    const float* __restrict__ W1, const float* __restrict__ b1,
    const float* __restrict__ W2, const float* __restrict__ b2,
    const float* __restrict__ W3, const float* __restrict__ b3,
    float* __restrict__ out)
{
    const int r = blockIdx.x * 256 + threadIdx.x;        // 0..131071, exact

    // ---- layer 1: own row, 31 iters x 10 k's; W1 chunk via s_load ----
    const f32x2* xr = (const f32x2*)(x + (size_t)r * 310);   // 1240 B stride: 8B-aligned
    float acc[10] = {0,0,0,0,0,0,0,0,0,0};
    #pragma unroll 1
    for (int kc = 0; kc < 31; ++kc) {
        f32x2 xv[5];
        #pragma unroll
        for (int i = 0; i < 5; ++i) xv[i] = xr[kc * 5 + i];  // global_load_dwordx2
        const float* wb = W1 + kc * 100;                     // wave-uniform
        #pragma unroll
        for (int kk = 0; kk < 10; ++kk) {
            const float xs = (kk & 1) ? xv[kk >> 1].y : xv[kk >> 1].x;
            #pragma unroll
            for (int j = 0; j < 10; ++j)
                acc[j] = fmaf(xs, wb[kk * 10 + j], acc[j]);  // v_fmac, SGPR weight
        }
    }
    float h1[10];
    #pragma unroll
    for (int j = 0; j < 10; ++j) h1[j] = leaky(acc[j] + b1[j]);

    // ---- layer 2 (10->128) fused with layer 3 (128->2), 8 chunks of 16 ----
    float c0 = b3[0], c1 = b3[1];
    #pragma unroll 1
    for (int jc = 0; jc < 8; ++jc) {
        float hh[16];
        #pragma unroll
        for (int m = 0; m < 16; ++m) hh[m] = b2[jc * 16 + m];
        #pragma unroll
        for (int k = 0; k < 10; ++k) {
            const float* w2b = W2 + k * 128 + jc * 16;       // wave-uniform
            #pragma unroll
            for (int m = 0; m < 16; ++m)
                hh[m] = fmaf(h1[k], w2b[m], hh[m]);
        }
        const float* w3b = W3 + jc * 32;                     // wave-uniform
        #pragma unroll
        for (int m = 0; m < 16; ++m) {
            const float s = leaky(hh[m]);
            c0 = fmaf(s, w3b[2 * m + 0], c0);
            c1 = fmaf(s, w3b[2 * m + 1], c1);
        }
    }
    c0 = leaky(c0);
    c1 = leaky(c1);

    // ---- epilogue: own 100-float span, 16B-aligned (400 B stride) ----
    const f32x4* dt = (const f32x4*)(data_t + (size_t)r * 100);
    f32x4*       o  = (f32x4*)(out    + (size_t)r * 100);
    #pragma unroll
    for (int i = 0; i < 25; ++i) {
        const f32x4 tt = dt[i];
        o[i] = tt * (tt * c1 + c0);      // t*(c0 + c1*t)
    }
}

extern "C" void kernel_launch(void* const* d_in, const int* in_sizes, int n_in,
                              void* d_out, int out_size, void* d_ws, size_t ws_size,
                              hipStream_t stream) {
    const float* x      = (const float*)d_in[0];
    const float* data_t = (const float*)d_in[1];
    const float* W1     = (const float*)d_in[2];
    const float* b1     = (const float*)d_in[3];
    const float* W2     = (const float*)d_in[4];
    const float* b2     = (const float*)d_in[5];
    const float* W3     = (const float*)d_in[6];
    const float* b3     = (const float*)d_in[7];
    float* out = (float*)d_out;

    // 512 blocks x 256 threads = 131072 threads, one row each.
    gen_mlp_r8<<<512, 256, 0, stream>>>(x, data_t, W1, b1, W2, b2, W3, b3, out);
}

// Round 9
// 59.789 us; speedup vs baseline: 1.5868x; 1.5868x over previous
//
#include <hip/hip_runtime.h>
#include <stdint.h>

typedef float f32x2 __attribute__((ext_vector_type(2)));
typedef float f32x4 __attribute__((ext_vector_type(4)));

#define TILE_F 19840      // 64 rows x 310 floats
#define NTPB   4          // tiles per block
#define PSTR   84         // h1-partial stride (dwords)
#define CP_OFF 5376       // coeff-partial region offset (dwords), past partials
#define CPSTR  20         // coeff-partial stride: 80 B, 16B-aligned
#define LDSF   (TILE_F + 128)          // + ccs scratch
#define LDS_BYTES (LDSF * 4)           // 79,872 B -> 2 blocks/CU

__device__ __forceinline__ float leaky(float v) { return fmaxf(v, 0.01f * v); }
__device__ __forceinline__ f32x2 leaky2(f32x2 v) {
    return __builtin_elementwise_max(v, v * 0.01f);
}

// L1 partial: KQ k's of this thread's row, 8-float register window.
template<int KQ>
__device__ __forceinline__ void l1_fma(const float* xr, const float* __restrict__ Wb,
                                       float* acc) {
    #pragma unroll
    for (int q = 0; q < (KQ + 7) / 8; ++q) {
        f32x2 xp[4];
        #pragma unroll
        for (int i = 0; i < 4; ++i)
            if (q * 8 + 2 * i < KQ) xp[i] = *(const f32x2*)(xr + q * 8 + 2 * i);
        #pragma unroll
        for (int k = 0; k < 8; ++k) {
            if (q * 8 + k < KQ) {
                const float xs = (k & 1) ? xp[k >> 1].y : xp[k >> 1].x;
                #pragma unroll
                for (int j = 0; j < 10; ++j)
                    acc[j] = fmaf(xs, Wb[(q * 8 + k) * 10 + j], acc[j]); // SGPR weight
            }
        }
    }
}

__global__ __launch_bounds__(512, 4) void gen_mlp_r9(
    const float* __restrict__ x, const float* __restrict__ data_t,
    const float* __restrict__ W1, const float* __restrict__ b1,
    const float* __restrict__ W2, const float* __restrict__ b2,
    const float* __restrict__ W3, const float* __restrict__ b3,
    float* __restrict__ out)
{
    extern __shared__ float lds[];
    float* buf = lds;                 // [0, TILE_F): x tile, then aliased scratch
    float* ccs = lds + TILE_F;        // 128 floats: final (c0,c1) per row

    const int t    = threadIdx.x;
    const int lane = t & 63;
    const int row  = lane;                                    // lane = row
    const int wq   = __builtin_amdgcn_readfirstlane(t >> 6);  // wave 0..7 = k-eighth

    const int tile0 = blockIdx.x * NTPB;

    // ---- prologue: stage tile0 (coalesced dwordx4, 1024B/wave-instr) ----
    {
        const float* g = x + (size_t)tile0 * TILE_F;
        #pragma unroll
        for (int i = 0; i < 10; ++i) {
            const int gi = i * 2048 + t * 4;
            if (gi < TILE_F) *(f32x4*)(buf + gi) = *(const f32x4*)(g + gi);
        }
    }
    asm volatile("s_waitcnt lgkmcnt(0)" ::: "memory");
    __builtin_amdgcn_s_barrier();

    #pragma unroll 1
    for (int it = 0; it < NTPB; ++it) {
        const int tile = tile0 + it;
        const bool pf  = (it + 1 < NTPB);

        // ---- 1. prefetch next x-tile into registers (T14 issue-early) ----
        f32x4 px[10];
        {
            const float* gn = x + (size_t)(tile + 1) * TILE_F;
            #pragma unroll
            for (int i = 0; i < 10; ++i) {
                const int gi = i * 2048 + t * 4;
                if (pf && gi < TILE_F) px[i] = *(const f32x4*)(gn + gi);
            }
        }

        // ---- 2. L1: my k-eighth, own row; weights via s_load (SGPR) ----
        float acc[10] = {0,0,0,0,0,0,0,0,0,0};
        const float* xr = buf + row * 310 + wq * 40;
        if (wq == 7) l1_fma<30>(xr, W1 + 2800, acc);
        else         l1_fma<40>(xr, W1 + wq * 400, acc);

        asm volatile("s_waitcnt lgkmcnt(0)" ::: "memory");
        __builtin_amdgcn_s_barrier();     // (a0) all x reads done -> alias ok

        {   // ---- 4. write h1 partials [row][wq][10] ----
            float* pw = buf + row * PSTR + wq * 10;
            #pragma unroll
            for (int j = 0; j < 5; ++j)
                *(f32x2*)(pw + 2 * j) = (f32x2){acc[2 * j], acc[2 * j + 1]};
        }
        asm volatile("s_waitcnt lgkmcnt(0)" ::: "memory");
        __builtin_amdgcn_s_barrier();     // (a)

        // ---- 6. data_t loads (cover = h1 + L2 + 2 barriers) ----
        const f32x4* dt4 = (const f32x4*)data_t + (size_t)tile * 1600;
        f32x4 tv0 = dt4[t], tv1 = dt4[512 + t], tv2 = dt4[1024 + t], tv3;
        if (t < 64) tv3 = dt4[1536 + t];

        // ---- 7. h1 = leaky(sum of 8 partials + b1), low-reg b64 window ----
        float h1[10];
        {
            const float* pr = buf + row * PSTR;
            float s[10];
            #pragma unroll
            for (int j = 0; j < 10; ++j) s[j] = b1[j];
            #pragma unroll
            for (int sl = 0; sl < 8; ++sl) {
                #pragma unroll
                for (int m = 0; m < 5; ++m) {
                    f32x2 v = *(const f32x2*)(pr + sl * 10 + 2 * m);
                    s[2 * m]     += v.x;
                    s[2 * m + 1] += v.y;
                }
            }
            #pragma unroll
            for (int j = 0; j < 10; ++j) h1[j] = leaky(s[j]);
        }

        // ---- 8. L2 j-slice (16 outs) + L3 partial; weights via s_load ----
        float hh[16];
        #pragma unroll
        for (int jj = 0; jj < 16; ++jj) hh[jj] = b2[wq * 16 + jj];
        #pragma unroll
        for (int k = 0; k < 10; ++k) {
            #pragma unroll
            for (int jj = 0; jj < 16; ++jj)
                hh[jj] = fmaf(h1[k], W2[k * 128 + wq * 16 + jj], hh[jj]);
        }
        f32x2 p = {0.f, 0.f};
        #pragma unroll
        for (int jj = 0; jj < 16; ++jj) {
            const float s = leaky(hh[jj]);
            p.x = fmaf(s, W3[(wq * 16 + jj) * 2 + 0], p.x);
            p.y = fmaf(s, W3[(wq * 16 + jj) * 2 + 1], p.y);
        }

        // ---- 9. coeff partials [row][wq] (disjoint from h1-partials) ----
        *(f32x2*)(buf + CP_OFF + row * CPSTR + 2 * wq) = p;
        asm volatile("s_waitcnt lgkmcnt(0)" ::: "memory");
        __builtin_amdgcn_s_barrier();     // (b)

        // ---- 11. final coeff by wave 0 (4 x b128, 16B-aligned) ----
        if (wq == 0) {
            const float* cb = buf + CP_OFF + row * CPSTR;
            f32x2 q = {b3[0], b3[1]};
            #pragma unroll
            for (int i = 0; i < 4; ++i) {
                f32x4 v = *(const f32x4*)(cb + 4 * i);
                q.x += v[0] + v[2];
                q.y += v[1] + v[3];
            }
            *(f32x2*)(ccs + 2 * row) = leaky2(q);
        }
        asm volatile("s_waitcnt lgkmcnt(0)" ::: "memory");
        __builtin_amdgcn_s_barrier();     // (b2)

        // ---- 13. stage-write prefetched tile (all buf readers done) ----
        if (pf) {
            #pragma unroll
            for (int i = 0; i < 10; ++i) {
                const int gi = i * 2048 + t * 4;
                if (gi < TILE_F) *(f32x4*)(buf + gi) = px[i];
            }
        }
        asm volatile("s_waitcnt lgkmcnt(0)" ::: "memory");
        __builtin_amdgcn_s_barrier();     // (w) next tile resident

        // ---- 14. epilogue: out = t*(c0 + c1*t); ccs reads drained by (a) ----
        f32x4* o4 = (f32x4*)out + (size_t)tile * 1600;
        {
            f32x2 cc = *(const f32x2*)(ccs + 2 * (t / 25) * 0 + 2 * ((0 * 512 + t) / 25));
            (void)cc;
        }
        #pragma unroll
        for (int i = 0; i < 3; ++i) {
            const int idx = i * 512 + t;
            f32x2 cc = *(const f32x2*)(ccs + 2 * (idx / 25));
            f32x4 tt = (i == 0) ? tv0 : (i == 1) ? tv1 : tv2;
            o4[idx] = tt * (tt * cc.y + cc.x);
        }
        if (t < 64) {
            const int idx = 1536 + t;
            f32x2 cc = *(const f32x2*)(ccs + 2 * (idx / 25));
            o4[idx] = tv3 * (tv3 * cc.y + cc.x);
        }
    }
}

extern "C" void kernel_launch(void* const* d_in, const int* in_sizes, int n_in,
                              void* d_out, int out_size, void* d_ws, size_t ws_size,
                              hipStream_t stream) {
    const float* x      = (const float*)d_in[0];
    const float* data_t = (const float*)d_in[1];
    const float* W1     = (const float*)d_in[2];
    const float* b1     = (const float*)d_in[3];
    const float* W2     = (const float*)d_in[4];
    const float* b2     = (const float*)d_in[5];
    const float* W3     = (const float*)d_in[6];
    const float* b3     = (const float*)d_in[7];
    float* out = (float*)d_out;

    hipFuncSetAttribute((const void*)gen_mlp_r9,
                        hipFuncAttributeMaxDynamicSharedMemorySize, LDS_BYTES);
    // 512 blocks x 512 threads x 4 tiles of 64 rows = 131072 rows; 2 blocks/CU
    gen_mlp_r9<<<512, 512, LDS_BYTES, stream>>>(x, data_t, W1, b1, W2, b2, W3, b3, out);
}